// Round 5
// baseline (704.909 us; speedup 1.0000x reference)
//
#include <hip/hip_runtime.h>
#include <math.h>

#define D_MODEL 1024
#define D_FF    4096
#define NEXP    8
#define NTOK    8192
#define NASSIGN (NTOK*2)
#define NGBLK   (NTOK/4)   // gating blocks (4 tokens/block)

using short8 = __attribute__((ext_vector_type(8))) short;
using short4v = __attribute__((ext_vector_type(4))) short;
using f32x4  = __attribute__((ext_vector_type(4))) float;

__device__ __forceinline__ short f2bf(float f) {
  unsigned u = __float_as_uint(f);
  unsigned r = (u + 0x7fffu + ((u >> 16) & 1u)) >> 16;
  return (short)r;
}

__device__ __forceinline__ void gload_lds16(const void* g, void* l) {
  __builtin_amdgcn_global_load_lds((const __attribute__((address_space(1))) void*)g,
                                   (__attribute__((address_space(3))) void*)l, 16, 0, 0);
}

// fast erf-gelu: Abramowitz-Stegun 7.1.26, |eps| <= 1.5e-7
__device__ __forceinline__ float gelu_f(float x) {
  float z = 0.70710678118f * x;
  float a = fabsf(z);
  float t = 1.0f / (1.0f + 0.3275911f * a);
  float p = t * (0.254829592f + t * (-0.284496736f + t * (1.421413741f +
            t * (-1.453152027f + t * 1.061405429f))));
  float er = 1.0f - p * __expf(-a * a);
  er = copysignf(er, z);
  return 0.5f * x * (1.0f + er);
}

// ---------------- zero control ----------------
__global__ void zero_kernel(int* ctrl) {
  int i = threadIdx.x;
  if (i < 24) ctrl[i] = 0;   // cnt[8], cursor[8], off[8]
}

// ---------------- transpose + convert: in[e][R][C] fp32 -> out[e][C][R] bf16 ----------------
__global__ __launch_bounds__(256) void transpose_conv(const float* __restrict__ in, short* __restrict__ out,
                                                      int R, int C) {
  __shared__ float t[64][65];
  int e = blockIdx.z;
  size_t base = (size_t)e * R * C;
  int r0 = blockIdx.y * 64, c0 = blockIdx.x * 64;
  int lr = threadIdx.x >> 6, lc = threadIdx.x & 63;
#pragma unroll
  for (int j = 0; j < 16; ++j) {
    int rr = lr + j * 4;
    t[rr][lc] = in[base + (size_t)(r0 + rr) * C + c0 + lc];
  }
  __syncthreads();
#pragma unroll
  for (int j = 0; j < 16; ++j) {
    int oc = lr + j * 4;
    out[base + (size_t)(c0 + oc) * R + r0 + lc] = f2bf(t[lc][oc]);
  }
}

// ---------------- gating: one wave per token; also emits xb (bf16 copy of x) ----------------
__global__ __launch_bounds__(256) void gating_kernel(const float* __restrict__ x, const float* __restrict__ Wg,
                                                     int* __restrict__ assign_e, float* __restrict__ assign_w,
                                                     int* __restrict__ cnt_part, float* __restrict__ psum_part,
                                                     ushort4* __restrict__ xb4) {
  __shared__ float l_ps[NEXP];
  __shared__ int   l_cnt[NEXP];
  int tid = threadIdx.x, wv = tid >> 6, lane = tid & 63;
  if (tid < NEXP) { l_ps[tid] = 0.f; l_cnt[tid] = 0; }
  __syncthreads();

  int t = blockIdx.x * 4 + wv;
  const float4* xr = (const float4*)(x + (size_t)t * D_MODEL);
  float acc[NEXP];
#pragma unroll
  for (int e = 0; e < NEXP; ++e) acc[e] = 0.f;
#pragma unroll
  for (int i = 0; i < 4; ++i) {
    int c4 = lane + 64 * i;
    float4 v = xr[c4];
    ushort4 o;
    o.x = (unsigned short)f2bf(v.x); o.y = (unsigned short)f2bf(v.y);
    o.z = (unsigned short)f2bf(v.z); o.w = (unsigned short)f2bf(v.w);
    xb4[(size_t)t * 256 + c4] = o;
    const float* wr = Wg + c4 * 4 * NEXP;
#pragma unroll
    for (int j = 0; j < 4; ++j) {
      float xv = (&v.x)[j];
#pragma unroll
      for (int e = 0; e < NEXP; ++e) acc[e] += xv * wr[j * NEXP + e];
    }
  }
#pragma unroll
  for (int off = 32; off; off >>= 1)
#pragma unroll
    for (int e = 0; e < NEXP; ++e) acc[e] += __shfl_down(acc[e], off);

  if (lane == 0) {
    float m = acc[0];
#pragma unroll
    for (int e = 1; e < NEXP; ++e) m = fmaxf(m, acc[e]);
    float p[NEXP], s = 0.f;
#pragma unroll
    for (int e = 0; e < NEXP; ++e) { p[e] = expf(acc[e] - m); s += p[e]; }
    float inv = 1.f / s;
#pragma unroll
    for (int e = 0; e < NEXP; ++e) p[e] *= inv;
    int i0 = 0; float v0 = p[0];
#pragma unroll
    for (int e = 1; e < NEXP; ++e) if (p[e] > v0) { v0 = p[e]; i0 = e; }
    int i1 = -1; float v1 = -1.f;
#pragma unroll
    for (int e = 0; e < NEXP; ++e) if (e != i0 && p[e] > v1) { v1 = p[e]; i1 = e; }
    float denom = 1.f / (v0 + v1 + 1e-9f);
    assign_e[2 * t] = i0;     assign_w[2 * t] = v0 * denom;
    assign_e[2 * t + 1] = i1; assign_w[2 * t + 1] = v1 * denom;
    atomicAdd(&l_cnt[i0], 1);
    atomicAdd(&l_cnt[i1], 1);
#pragma unroll
    for (int e = 0; e < NEXP; ++e) atomicAdd(&l_ps[e], p[e]);
  }
  __syncthreads();
  if (tid < NEXP) {
    psum_part[blockIdx.x * NEXP + tid] = l_ps[tid];
    cnt_part[blockIdx.x * NEXP + tid] = l_cnt[tid];
  }
}

// ---------------- scan: reduce partials -> cnt/offs + aux loss ----------------
__global__ __launch_bounds__(256) void scan_kernel(const int* __restrict__ cnt_part, const float* __restrict__ psum_part,
                                                   int* __restrict__ cnt, int* __restrict__ offs,
                                                   float* __restrict__ aux_out) {
  __shared__ float sp[256];
  __shared__ int   sc[256];
  int tid = threadIdx.x;
  int e = tid & 7, c = tid >> 3;
  float fs = 0.f; int is = 0;
  for (int b = c; b < NGBLK; b += 32) {
    fs += psum_part[b * NEXP + e];
    is += cnt_part[b * NEXP + e];
  }
  sp[tid] = fs; sc[tid] = is;
  __syncthreads();
  if (tid < NEXP) {
    float f = 0.f; int n = 0;
    for (int c2 = 0; c2 < 32; ++c2) { f += sp[c2 * 8 + tid]; n += sc[c2 * 8 + tid]; }
    cnt[tid] = n; sp[tid] = f;
  }
  __syncthreads();
  if (tid == 0) {
    int o = 0; float aux = 0.f;
    for (int e2 = 0; e2 < NEXP; ++e2) {
      offs[e2] = o; o += cnt[e2];
      aux += (float)cnt[e2] * sp[e2];
    }
    aux_out[0] = aux * (float)NEXP / ((float)NTOK * (float)NTOK);
  }
}

// ---------------- scatter: compact assignments per expert ----------------
__global__ __launch_bounds__(256) void scatter_kernel(const int* __restrict__ assign_e,
                                                      const int* __restrict__ offs, int* __restrict__ cursor,
                                                      int* __restrict__ slot_tok, int* __restrict__ slot_of) {
  __shared__ int lhist[NEXP], lbase[NEXP];
  int tid = threadIdx.x;
  int a = blockIdx.x * 256 + tid;
  if (tid < NEXP) lhist[tid] = 0;
  __syncthreads();
  int e = assign_e[a];
  int lp = atomicAdd(&lhist[e], 1);
  __syncthreads();
  if (tid < NEXP) lbase[tid] = atomicAdd(&cursor[tid], lhist[tid]);
  __syncthreads();
  int s = offs[e] + lbase[e] + lp;
  slot_tok[s] = a >> 1;
  slot_of[a] = s;
}

// ================= 256x256 tile, BK=32, double-buffer, single-barrier 2-phase =================
// Schedule proven race-free in R4 (stage-next FIRST -> 12x ds_read -> 32 MFMA -> vmcnt(0) -> barrier).
// 256^2 tile restores L3-covered traffic (R3: fetch ~= compulsory). 8 waves (2M x 4N), 64 KiB LDS.
// k-slot swizzle (0 conflicts, R3/R4-verified): chunk c of row r lives at slot c ^ ((r>>1)&3).
// XCD-bijective 1D grid, rt-fast within expert: each XCD owns one expert; B panel L2-resident.
template<int KD, int ND, int EPI>
__global__ __launch_bounds__(512, 2) void gemm256(
    const short* __restrict__ Asrc, const short* __restrict__ Bsrc,
    const float* __restrict__ bias, const int* __restrict__ slot_tok,
    const int* __restrict__ cnt, const int* __restrict__ offs,
    void* __restrict__ OutP)
{
  constexpr int NT = KD / 32;
  constexpr int FT = ND / 256;
  constexpr int TOT = FT * 32 * NEXP;
  extern __shared__ __align__(16) short lds[];   // A: [2][8192], B: [2][8192] at +16384

  // bijective XCD swizzle (TOT % 8 == 0), rt-fast work order within expert
  int bid = blockIdx.x;
  int widx = (bid & 7) * (TOT / 8) + (bid >> 3);
  int e = widx / (FT * 32);
  int r = widx - e * (FT * 32);
  int ft = r >> 5;
  int rt = r & 31;
  int cn = cnt[e];
  if (rt * 256 >= cn) return;
  int off = offs[e];
  int tid = threadIdx.x, l = tid & 63, w = tid >> 6;
  int wm = w >> 2, wn = w & 3, l15 = l & 15;

  // staging: thread covers rows srow and srow+128; source k-chunk pre-swizzled
  int srow = tid >> 2;
  int sw8 = ((tid & 3) ^ ((tid >> 3) & 3)) * 8;
  int g0 = rt * 256 + srow, g1 = g0 + 128;
  int i0 = g0 < cn ? g0 : cn - 1;
  int i1 = g1 < cn ? g1 : cn - 1;
  const short *a0, *a1;
  if (EPI == 0) {
    a0 = Asrc + (size_t)slot_tok[off + i0] * KD + sw8;
    a1 = Asrc + (size_t)slot_tok[off + i1] * KD + sw8;
  } else {
    a0 = Asrc + (size_t)(off + i0) * KD + sw8;
    a1 = Asrc + (size_t)(off + i1) * KD + sw8;
  }
  const short* bb = Bsrc + (size_t)e * ND * KD + (size_t)(ft * 256) * KD + sw8;
  const short* b0 = bb + (size_t)srow * KD;
  const short* b1 = bb + (size_t)(srow + 128) * KD;
  short* Ab = lds;            // bytes: buf b at b*16384
  short* Bb = lds + 16384;

  // prologue: stage tile 0 into buf 0
  gload_lds16(a0, (char*)Ab + tid * 16); gload_lds16(a1, (char*)Ab + 8192 + tid * 16);
  gload_lds16(b0, (char*)Bb + tid * 16); gload_lds16(b1, (char*)Bb + 8192 + tid * 16);
  a0 += 32; a1 += 32; b0 += 32; b1 += 32;
  asm volatile("s_waitcnt vmcnt(0)" ::: "memory");
  __syncthreads();

  int cs8 = ((l >> 4) ^ ((l >> 1) & 3)) * 8;   // read slot = wanted k-group XOR row-swizzle
  const short* Ard = Ab + (wm * 128 + l15) * 32 + cs8;
  const short* Brd = Bb + (wn * 64 + l15) * 32 + cs8;
  f32x4 acc[8][4] = {};

  for (int t = 0; t < NT; ++t) {
    int cur = t & 1;
    if (t + 1 < NT) {   // stage next tile FIRST (latency hides under reads+MFMA)
      char* dA = (char*)Ab + (cur ^ 1) * 16384 + tid * 16;
      char* dB = (char*)Bb + (cur ^ 1) * 16384 + tid * 16;
      gload_lds16(a0, dA); gload_lds16(a1, dA + 8192);
      gload_lds16(b0, dB); gload_lds16(b1, dB + 8192);
      a0 += 32; a1 += 32; b0 += 32; b1 += 32;
    }
    const short* Ac = Ard + cur * 8192;
    const short* Bc = Brd + cur * 8192;
    short8 af[8], bq[4];
#pragma unroll
    for (int n = 0; n < 4; ++n) bq[n] = *(const short8*)(Bc + n * 512);
#pragma unroll
    for (int m = 0; m < 8; ++m) af[m] = *(const short8*)(Ac + m * 512);
    __builtin_amdgcn_s_setprio(1);
#pragma unroll
    for (int m = 0; m < 8; ++m)
#pragma unroll
      for (int n = 0; n < 4; ++n)   // transposed-C: D rows = f/d cols, D cols = tokens
        acc[m][n] = __builtin_amdgcn_mfma_f32_16x16x32_bf16(bq[n], af[m], acc[m][n], 0, 0, 0);
    __builtin_amdgcn_s_setprio(0);
    asm volatile("s_waitcnt vmcnt(0)" ::: "memory");
    __syncthreads();
  }

  // epilogue: acc[m][n][j] -> out[tok = rt*256+wm*128+m*16+l15][col = ft*256+wn*64+n*16+(l>>4)*4+j]
  int l4 = (l >> 4) << 2;
#pragma unroll
  for (int n = 0; n < 4; ++n) {
    int col = ft * 256 + wn * 64 + n * 16 + l4;
    f32x4 b4 = *(const f32x4*)&bias[e * ND + col];
#pragma unroll
    for (int m = 0; m < 8; ++m) {
      int tok = rt * 256 + wm * 128 + m * 16 + l15;
      if (tok < cn) {
        if (EPI == 0) {
          short4v h;
#pragma unroll
          for (int j = 0; j < 4; ++j) h[j] = f2bf(gelu_f(acc[m][n][j] + b4[j]));
          *(short4v*)((short*)OutP + (size_t)(off + tok) * ND + col) = h;
        } else {
          f32x4 o;
#pragma unroll
          for (int j = 0; j < 4; ++j) o[j] = acc[m][n][j] + b4[j];
          *(f32x4*)((float*)OutP + (size_t)(off + tok) * ND + col) = o;
        }
      }
    }
  }
}

// ---------------- combine: out[t] = w0*y[s0] + w1*y[s1] ----------------
__global__ __launch_bounds__(256) void combine_kernel(const float* __restrict__ y, const int* __restrict__ slot_of,
                                                      const float* __restrict__ assign_w, float* __restrict__ out) {
  int t = blockIdx.x;
  int d4 = threadIdx.x;
  int s0 = slot_of[2 * t], s1 = slot_of[2 * t + 1];
  float w0 = assign_w[2 * t], w1 = assign_w[2 * t + 1];
  float4 a = ((const float4*)(y + (size_t)s0 * D_MODEL))[d4];
  float4 b = ((const float4*)(y + (size_t)s1 * D_MODEL))[d4];
  float4 o;
  o.x = w0 * a.x + w1 * b.x;
  o.y = w0 * a.y + w1 * b.y;
  o.z = w0 * a.z + w1 * b.z;
  o.w = w0 * a.w + w1 * b.w;
  ((float4*)(out + (size_t)t * D_MODEL))[d4] = o;
}

extern "C" void kernel_launch(void* const* d_in, const int* in_sizes, int n_in,
                              void* d_out, int out_size, void* d_ws, size_t ws_size,
                              hipStream_t stream) {
  const float* x  = (const float*)d_in[0];
  const float* Wg = (const float*)d_in[1];
  const float* W1 = (const float*)d_in[2];
  const float* b1 = (const float*)d_in[3];
  const float* W2 = (const float*)d_in[4];
  const float* b2 = (const float*)d_in[5];
  float* out = (float*)d_out;
  char* ws = (char*)d_ws;

  // workspace layout (~285.6 MB)
  short* xb       = (short*)(ws);                       // 16,777,216 B
  short* w1t      = (short*)(ws + 16777216);            // 67,108,864 B  [e][f][k] bf16
  float* y        = (float*)(ws + 16777216);            // aliases w1t (dead after gemm1): 16384x1024 fp32
  short* w2t      = (short*)(ws + 83886080);            // 67,108,864 B  [e][d][ff] bf16
  short* H        = (short*)(ws + 150994944);           // 134,217,728 B 16384 x 4096 bf16
  int*   slot_tok = (int*)  (ws + 285212672);
  int*   assign_e = (int*)  (ws + 285278208);
  float* assign_w = (float*)(ws + 285343744);
  int*   slot_of  = (int*)  (ws + 285409280);
  int*   cnt_part = (int*)  (ws + 285474816);
  float* psum_part= (float*)(ws + 285540352);
  int*   ctrl     = (int*)  (ws + 285605888);
  int* cnt = ctrl; int* cursor = ctrl + 8; int* offs = ctrl + 16;

  hipFuncSetAttribute(reinterpret_cast<const void*>(&gemm256<D_MODEL, D_FF, 0>),
                      hipFuncAttributeMaxDynamicSharedMemorySize, 65536);
  hipFuncSetAttribute(reinterpret_cast<const void*>(&gemm256<D_FF, D_MODEL, 1>),
                      hipFuncAttributeMaxDynamicSharedMemorySize, 65536);

  zero_kernel<<<1, 64, 0, stream>>>(ctrl);
  transpose_conv<<<dim3(64, 16, NEXP), 256, 0, stream>>>(W1, w1t, D_MODEL, D_FF);
  transpose_conv<<<dim3(16, 64, NEXP), 256, 0, stream>>>(W2, w2t, D_FF, D_MODEL);
  gating_kernel<<<NGBLK, 256, 0, stream>>>(x, Wg, assign_e, assign_w, cnt_part, psum_part,
                                           (ushort4*)xb);
  scan_kernel<<<1, 256, 0, stream>>>(cnt_part, psum_part, cnt, offs, out + (out_size - 1));
  scatter_kernel<<<NASSIGN / 256, 256, 0, stream>>>(assign_e, offs, cursor, slot_tok, slot_of);
  gemm256<D_MODEL, D_FF, 0><<<(D_FF / 256) * 32 * NEXP, 512, 65536, stream>>>(
      xb, w1t, b1, slot_tok, cnt, offs, H);
  gemm256<D_FF, D_MODEL, 1><<<(D_MODEL / 256) * 32 * NEXP, 512, 65536, stream>>>(
      H, w2t, b2, slot_tok, cnt, offs, y);
  combine_kernel<<<NTOK, 256, 0, stream>>>(y, slot_of, assign_w, out);
}